// Round 7
// baseline (1023.167 us; speedup 1.0000x reference)
//
#include <hip/hip_runtime.h>
#include <math.h>

#define BB 4096
#define HH 1024
#define RR 10
#define MIDD 512
#define D3 3072

typedef __bf16 bf16x8 __attribute__((ext_vector_type(8)));
typedef __bf16 bf16x4 __attribute__((ext_vector_type(4)));
typedef float f32x4 __attribute__((ext_vector_type(4)));

// ---------------- reduction helpers ----------------
__device__ __forceinline__ float waveSum(float v){
#pragma unroll
  for(int o=32;o>0;o>>=1) v += __shfl_down(v,o,64);
  return v;
}
__device__ __forceinline__ float blockSum256(float v, float* sc){
  v = waveSum(v);
  __syncthreads();
  if((threadIdx.x & 63)==0) sc[threadIdx.x>>6] = v;
  __syncthreads();
  return sc[0]+sc[1]+sc[2]+sc[3];
}
__device__ __forceinline__ float gelu_f(float x){
  return 0.5f*x*(1.0f+erff(x*0.70710678118654752f));
}
__device__ __forceinline__ void gl_lds16(const void* g, void* lds){
  __builtin_amdgcn_global_load_lds((const __attribute__((address_space(1))) unsigned int*)g,
                                   (__attribute__((address_space(3))) unsigned int*)lds,
                                   16, 0, 0);
}

// ================= prep_k: convw + transpose_factors + feat_go ==============
// blocks [0,6144): weight converts; [6144,16384): factor transpose;
// [16384,28672): gate-others features (+audioB, gpre=0).
__global__ void prep_k(const float* __restrict__ go_w1, __bf16* __restrict__ go_w1B,
                       const float* __restrict__ ga_w1, __bf16* __restrict__ ga_w1B,
                       const float* __restrict__ a2o_w, __bf16* __restrict__ a2o_wB,
                       const float* __restrict__ o2a_w, __bf16* __restrict__ o2a_wB,
                       const float* __restrict__ out_w, __bf16* __restrict__ out_wB,
                       const float* __restrict__ factors, __bf16* __restrict__ factT,
                       const float* __restrict__ tokens, const int* __restrict__ mask,
                       const float* __restrict__ lnw, const float* __restrict__ lnb,
                       __bf16* __restrict__ featGo, __bf16* __restrict__ audioB,
                       float* __restrict__ gpre){
  __shared__ float T[64][65];   // transpose tile; feat_go reuses T[0][0..3] as sc
  const int b = blockIdx.x;
  const int tid = threadIdx.x;

  if(b < 6144){
    const int n0=MIDD*D3, n1=MIDD*D3, n2=HH*HH, n3=HH*HH, n4=HH*HH;
    long i = ((long)b*256 + tid)*4;
    const float* s; __bf16* d;
    if(i<n0){ s=go_w1; d=go_w1B; }
    else { i-=n0; if(i<n1){ s=ga_w1; d=ga_w1B; }
    else { i-=n1; if(i<n2){ s=a2o_w; d=a2o_wB; }
    else { i-=n2; if(i<n3){ s=o2a_w; d=o2a_wB; }
    else { i-=n3; if(i>=n4) return; s=out_w; d=out_wB; } } } }
    float4 v=*(const float4*)(s+i);
    bf16x4 o; o[0]=(__bf16)v.x; o[1]=(__bf16)v.y; o[2]=(__bf16)v.z; o[3]=(__bf16)v.w;
    *(bf16x4*)(d+i)=o;
    return;
  }
  if(b < 16384){
    int id = b - 6144;
    int h0 = (id & 15)*64;
    int d0 = ((id >> 4) & 15)*64;
    int mr = id >> 8;
    int rr = tid>>4, cc = (tid&15)*4;
    const float* src = factors + ((size_t)mr*1025 + 1 + d0)*1024 + h0;
#pragma unroll
    for(int q=0;q<4;q++){
      float4 v = *(const float4*)(src + (size_t)(q*16+rr)*1024 + cc);
      T[q*16+rr][cc]=v.x; T[q*16+rr][cc+1]=v.y; T[q*16+rr][cc+2]=v.z; T[q*16+rr][cc+3]=v.w;
    }
    __syncthreads();
    __bf16* dst = factT + ((size_t)mr*1024 + h0)*1024 + d0;
#pragma unroll
    for(int q=0;q<4;q++){
      int hr = q*16 + rr;
      bf16x4 o;
      o[0]=(__bf16)T[cc][hr];   o[1]=(__bf16)T[cc+1][hr];
      o[2]=(__bf16)T[cc+2][hr]; o[3]=(__bf16)T[cc+3][hr];
      *(bf16x4*)(dst + (size_t)hr*1024 + cc) = o;
    }
    return;
  }
  {
    int row = b - 16384;
    int bb_ = row/3; int j = row - bb_*3; int oj = (j==0)?0:(j+1);
    if(tid==0) gpre[row]=0.f;
    const float* to=tokens+((size_t)bb_*4+oj)*HH;
    const float* ta=tokens+((size_t)bb_*4+1)*HH;
    float mo = mask[bb_*4+oj]?1.f:0.f;
    float* sc = &T[0][0];
    float ov[4], av[4], dv[4]; float s=0.f,s2=0.f;
#pragma unroll
    for(int p=0;p<4;p++){
      int h=tid+p*256;
      float o=to[h]*mo, a=ta[h], d=fabsf(o-a);
      ov[p]=o; av[p]=a; dv[p]=d;
      s+=o+a+d; s2+=o*o+a*a+d*d;
    }
    s=blockSum256(s,sc); s2=blockSum256(s2,sc);
    float mean=s/(float)D3, rstd=rsqrtf(s2/(float)D3-mean*mean+1e-5f);
    __bf16* fr = featGo + (size_t)row*D3;
#pragma unroll
    for(int p=0;p<4;p++){
      int h=tid+p*256;
      fr[h]       =(__bf16)((ov[p]-mean)*rstd*lnw[h]+lnb[h]);
      fr[1024+h]  =(__bf16)((av[p]-mean)*rstd*lnw[1024+h]+lnb[1024+h]);
      fr[2048+h]  =(__bf16)((dv[p]-mean)*rstd*lnw[2048+h]+lnb[2048+h]);
      if(j==0) audioB[(size_t)bb_*HH+h]=(__bf16)av[p];
    }
  }
}

// ================= dual-descriptor 128x128 bf16 MFMA NT GEMM ================
// act=0: C=A@B^T. act=1: C=gelu(A@B^T+bias). act=2: atomic gate-dot into gpre.
// 128x128 tile, BK=32, 4 waves (4x4 frags/wave: best ds_read/MFMA ratio),
// 3-buf depth-2 counted-vmcnt(4), XCD swizzle per segment. LDS 48KB -> 3 blk/CU.
struct GD {
  const __bf16* A; const __bf16* B;
  const float* bias; float* C;
  const float* w2; float* gpre;
  int lda, ldb, ldc, K, nbx, nby, act;
};

__launch_bounds__(256, 3)
__global__ void gemm_dual_k(GD d0, GD d1, int n0){
  __shared__ __align__(16) __bf16 As[3*4096];
  __shared__ __align__(16) __bf16 Bs[3*4096];
  const int tid=threadIdx.x, l=tid&63, w=tid>>6;
  const int wr=w>>1, wc=w&1;
  const int quad=l>>4, lr16=l&15;

  GD d; int lb;
  if((int)blockIdx.x < n0){ d = d0; lb = blockIdx.x; }
  else                    { d = d1; lb = blockIdx.x - n0; }

  const int chunk = (d.nbx*d.nby)>>3;
  const int nid = (lb&7)*chunk + (lb>>3);
  const int bx = nid % d.nbx, by = nid / d.nbx;
  const int row0=by*128, col0=bx*128;

  const int srow=l>>2, sq=(l&3)^((l>>3)&3);
  const int nsteps = d.K>>5;

  const __bf16* pa0 = d.A + (size_t)(row0 + w*16     + srow)*d.lda + sq*8;
  const __bf16* pa1 = d.A + (size_t)(row0 + (w+4)*16 + srow)*d.lda + sq*8;
  const __bf16* pb0 = d.B + (size_t)(col0 + w*16     + srow)*d.ldb + sq*8;
  const __bf16* pb1 = d.B + (size_t)(col0 + (w+4)*16 + srow)*d.ldb + sq*8;
  __bf16* da0 = As + ((size_t)w*64     + l)*8;
  __bf16* da1 = As + ((size_t)(w+4)*64 + l)*8;
  __bf16* db0 = Bs + ((size_t)w*64     + l)*8;
  __bf16* db1 = Bs + ((size_t)(w+4)*64 + l)*8;

  auto stage=[&](int s,int bi){
    int k0 = s*32;
    gl_lds16(pa0 + k0, da0 + bi*4096);
    gl_lds16(pa1 + k0, da1 + bi*4096);
    gl_lds16(pb0 + k0, db0 + bi*4096);
    gl_lds16(pb1 + k0, db1 + bi*4096);
  };

  f32x4 acc[4][4];
  f32x4 zerov={0.f,0.f,0.f,0.f};
#pragma unroll
  for(int i=0;i<4;i++)
#pragma unroll
    for(int j=0;j<4;j++) acc[i][j]=zerov;

  stage(0,0);
  stage(1,1);
  asm volatile("s_waitcnt vmcnt(4)" ::: "memory");
  __builtin_amdgcn_s_barrier();

  int cur=0;
  for(int step=0; step<nsteps; ++step){
    const __bf16* Ab = As + cur*4096;
    const __bf16* Bb = Bs + cur*4096;
    bf16x8 af[4], bg[4];
#pragma unroll
    for(int fi=0;fi<4;fi++){
      int R = wr*64 + fi*16 + lr16;
      af[fi]=*(const bf16x8*)(Ab + R*32 + ((quad^(R>>1))&3)*8);
    }
#pragma unroll
    for(int fj=0;fj<4;fj++){
      int N = wc*64 + fj*16 + lr16;
      bg[fj]=*(const bf16x8*)(Bb + N*32 + ((quad^(N>>1))&3)*8);
    }
    if(step+2<nsteps){
      int bi = cur + 2; if(bi>=3) bi-=3;
      stage(step+2, bi);
    }
    __builtin_amdgcn_s_setprio(1);
#pragma unroll
    for(int fi=0;fi<4;fi++)
#pragma unroll
      for(int fj=0;fj<4;fj++)
        acc[fi][fj]=__builtin_amdgcn_mfma_f32_16x16x32_bf16(af[fi],bg[fj],acc[fi][fj],0,0,0);
    __builtin_amdgcn_s_setprio(0);
    asm volatile("s_waitcnt lgkmcnt(0)" ::: "memory");
    if(step < nsteps-2) asm volatile("s_waitcnt vmcnt(4)" ::: "memory");
    else                asm volatile("s_waitcnt vmcnt(0)" ::: "memory");
    __builtin_amdgcn_s_barrier();
    cur = (cur+1==3)?0:cur+1;
  }

  if(d.act==2){
    float b1v[4], w2v[4];
#pragma unroll
    for(int fj=0;fj<4;fj++){
      int col=col0+wc*64+fj*16+lr16;
      b1v[fj]=d.bias[col]; w2v[fj]=d.w2[col];
    }
#pragma unroll
    for(int fi=0;fi<4;fi++){
#pragma unroll
      for(int reg=0;reg<4;reg++){
        float part=0.f;
#pragma unroll
        for(int fj=0;fj<4;fj++) part += gelu_f(acc[fi][fj][reg]+b1v[fj])*w2v[fj];
        part += __shfl_xor(part,1,64);
        part += __shfl_xor(part,2,64);
        part += __shfl_xor(part,4,64);
        part += __shfl_xor(part,8,64);
        if((l&15)==0) atomicAdd(&d.gpre[row0+wr*64+fi*16+quad*4+reg], part);
      }
    }
    return;
  }

  float bv[4];
#pragma unroll
  for(int fj=0;fj<4;fj++) bv[fj] = (d.act==1)? d.bias[col0+wc*64+fj*16+lr16] : 0.f;
#pragma unroll
  for(int fi=0;fi<4;fi++){
#pragma unroll
    for(int reg=0;reg<4;reg++){
      int row=row0+wr*64+fi*16+quad*4+reg;
#pragma unroll
      for(int fj=0;fj<4;fj++){
        int col=col0+wc*64+fj*16+lr16;
        float v=acc[fi][fj][reg];
        if(d.act==1) v=gelu_f(v+bv[fj]);
        d.C[(size_t)row*d.ldc+col]=v;
      }
    }
  }
}

// ------- others_new (mixedB 0,2,3) + omeanB + fused feat_ga + ga_pre=0 ------
__global__ void others_k(const float* __restrict__ tokens, const int* __restrict__ mask,
                         const float* __restrict__ gpre, const float* __restrict__ go_b2,
                         const float* __restrict__ a2o,
                         const float* __restrict__ lnw, const float* __restrict__ lnb,
                         const float* __restrict__ galnw, const float* __restrict__ galnb,
                         __bf16* __restrict__ mixedB, __bf16* __restrict__ omeanB,
                         __bf16* __restrict__ featGa, float* __restrict__ gapre){
  int b=blockIdx.x, tid=threadIdx.x;
  __shared__ float sc[4];
  if(tid==0) gapre[b]=0.f;
  float ma = mask[b*4+1]?1.f:0.f;
  float a2[4];
#pragma unroll
  for(int p=0;p<4;p++) a2[p]=a2o[(size_t)b*HH+tid+p*256];
  float sum[4]={0,0,0,0}; float cnt=0.f;
  for(int j=0;j<3;j++){
    int oj=(j==0)?0:(j+1);
    float mo=mask[b*4+oj]?1.f:0.f; cnt+=mo;
    float gv=1.f/(1.f+expf(-(gpre[b*3+j]+go_b2[0])));
    float t[4], ov[4]; float s=0.f,s2=0.f;
#pragma unroll
    for(int p=0;p<4;p++){
      int h=tid+p*256;
      float o=tokens[((size_t)b*4+oj)*HH+h]*mo;
      ov[p]=o; t[p]=o+gv*a2[p];
      s+=t[p]; s2+=t[p]*t[p];
    }
    s=blockSum256(s,sc); s2=blockSum256(s2,sc);
    float mean=s/1024.f, rstd=rsqrtf(s2/1024.f-mean*mean+1e-5f);
    float pv=mo*ma;
#pragma unroll
    for(int p=0;p<4;p++){
      int h=tid+p*256;
      float upd=(t[p]-mean)*rstd*lnw[h]+lnb[h];
      float on=((pv>0.5f)?upd:ov[p])*mo;
      mixedB[(size_t)b*4096 + (size_t)oj*HH + h]=(__bf16)on;
      sum[p]+=on*mo;
    }
  }
  float denom=fmaxf(cnt,1.f);
  float vm[4];
#pragma unroll
  for(int p=0;p<4;p++){
    vm[p]=sum[p]/denom;
    omeanB[(size_t)b*HH+tid+p*256]=(__bf16)vm[p];
  }
  const float* ta=tokens+((size_t)b*4+1)*HH;
  float tv[4], dv[4]; float s=0.f,s2=0.f;
#pragma unroll
  for(int p=0;p<4;p++){
    int h=tid+p*256;
    float a=ta[h], d=fabsf(a-vm[p]);
    tv[p]=a; dv[p]=d;
    s+=a+vm[p]+d; s2+=a*a+vm[p]*vm[p]+d*d;
  }
  s=blockSum256(s,sc); s2=blockSum256(s2,sc);
  float mean=s/(float)D3, rstd=rsqrtf(s2/(float)D3-mean*mean+1e-5f);
  __bf16* fr=featGa+(size_t)b*D3;
#pragma unroll
  for(int p=0;p<4;p++){
    int h=tid+p*256;
    fr[h]     =(__bf16)((tv[p]-mean)*rstd*galnw[h]+galnb[h]);
    fr[1024+h]=(__bf16)((vm[p]-mean)*rstd*galnw[1024+h]+galnb[1024+h]);
    fr[2048+h]=(__bf16)((dv[p]-mean)*rstd*galnw[2048+h]+galnb[2048+h]);
  }
}

// ------- mixed_audio (mixedB slot 1) + fused init to lmf_bias ---------------
__global__ void audio_k(const float* __restrict__ tokens, const int* __restrict__ mask,
                        const float* __restrict__ gapre, const float* __restrict__ ga_b2,
                        const float* __restrict__ o2a,
                        const float* __restrict__ lnw, const float* __restrict__ lnb,
                        __bf16* __restrict__ mixedB,
                        const float* __restrict__ lmf_bias, float* __restrict__ fused){
  int b=blockIdx.x, tid=threadIdx.x;
  __shared__ float sc[4];
  int ma_i=mask[b*4+1];
  int any = mask[b*4+0]|mask[b*4+2]|mask[b*4+3];
  bool aum = (ma_i!=0) && (any!=0);
  float ma = ma_i?1.f:0.f;
  float gv=1.f/(1.f+expf(-(gapre[b]+ga_b2[0])));
  const float* ta = tokens + ((size_t)b*4+1)*HH;
  float av[4], t[4]; float s=0.f,s2=0.f;
#pragma unroll
  for(int p=0;p<4;p++){
    int h=tid+p*256;
    av[p]=ta[h];
    t[p]=av[p]+gv*o2a[(size_t)b*HH+h];
    s+=t[p]; s2+=t[p]*t[p];
  }
  s=blockSum256(s,sc); s2=blockSum256(s2,sc);
  float mean=s/1024.f, rstd=rsqrtf(s2/1024.f-mean*mean+1e-5f);
#pragma unroll
  for(int p=0;p<4;p++){
    int h=tid+p*256;
    float u=(t[p]-mean)*rstd*lnw[h]+lnb[h];
    float outv = aum ? u : av[p]*ma;
    mixedB[(size_t)b*4096 + HH + h]=(__bf16)(outv*ma);
    fused[(size_t)b*HH + h]=lmf_bias[h];
  }
}

// -------- LMF: fused[b,h] += sum_{r in half} rank_w[r]*prod_m(mask? z : 1) --
// r INSIDE the block; no P buffer. 128x128 tile, 640 K-steps, 3-buf pipeline.
// XCD swizzle: XCD x owns {bz=x&1, by-group x>>1 (8 rows), all 8 hh} ->
// per-phase resident = 8 A-tiles (2MB) + 8 B-slices (2MB) = 4MB L2, both shared.
__launch_bounds__(256, 2)
__global__ void gemm_lmf2(const __bf16* __restrict__ mixedB,
                          const __bf16* __restrict__ factT,
                          const float* __restrict__ factors,
                          const int* __restrict__ mask,
                          const float* __restrict__ rank_w,
                          float* __restrict__ fused){
  __shared__ __align__(16) __bf16 As[3*4096];
  __shared__ __align__(16) __bf16 Bs[3*4096];
  __shared__ float Mskf[4][128];
  __shared__ float F0s[20][128];
  __shared__ float Rws[5];
  const int tid = threadIdx.x;
  const int l = tid & 63, w = tid >> 6;
  const int wr = w >> 1, wc = w & 1;
  const int quad = l >> 4, lr16 = l & 15;

  const int flat = blockIdx.x + 8*(blockIdx.y + 32*blockIdx.z);
  const int x    = flat & 7;         // XCD
  const int j    = flat >> 3;        // 0..63 within XCD
  const int bz   = x & 1;
  const int by   = (x >> 1)*8 + (j >> 3);
  const int hh   = j & 7;
  const int row0 = by * 128, col0 = hh * 128;
  const int z5   = bz * 5;

  const int srow = l >> 2;
  const int sq   = (l & 3) ^ ((l >> 3) & 3);

  for(int i = tid; i < 512; i += 256){
    int mm = i >> 7, rl = i & 127;
    Mskf[mm][rl] = mask[(row0 + rl)*4 + mm] ? 1.f : 0.f;
  }
  for(int i = tid; i < 2560; i += 256){
    int rm = i >> 7, cl = i & 127;
    int m = rm & 3, rg = z5 + (rm >> 2);
    F0s[rm][cl] = factors[(size_t)(m*RR + rg)*1025*1024 + col0 + cl];
  }
  if(tid < 5) Rws[tid] = rank_w[z5 + tid];

  const __bf16* pa0 = mixedB + (size_t)(row0 + w*16     + srow)*4096 + sq*8;
  const __bf16* pa1 = mixedB + (size_t)(row0 + (w+4)*16 + srow)*4096 + sq*8;
  const __bf16* pb0 = factT + ((size_t)(col0 + w*16     + srow))*1024 + sq*8;
  const __bf16* pb1 = factT + ((size_t)(col0 + (w+4)*16 + srow))*1024 + sq*8;
  __bf16* da0 = As + ((size_t)w*64     + l)*8;
  __bf16* da1 = As + ((size_t)(w+4)*64 + l)*8;
  __bf16* db0 = Bs + ((size_t)w*64     + l)*8;
  __bf16* db1 = Bs + ((size_t)(w+4)*64 + l)*8;

  auto stage = [&](int s, int bi){
    int rm = s >> 5, k0 = (s & 31)*32;
    int m = rm & 3, rg = z5 + (rm >> 2);
    size_t ao = (size_t)m*1024 + k0;
    size_t bo = (size_t)(m*RR + rg)*1048576 + k0;
    gl_lds16(pa0 + ao, da0 + bi*4096);
    gl_lds16(pa1 + ao, da1 + bi*4096);
    gl_lds16(pb0 + bo, db0 + bi*4096);
    gl_lds16(pb1 + bo, db1 + bi*4096);
  };

  f32x4 fsum[4][4];
  f32x4 prod[4][4];
  f32x4 acc[4][4];
  f32x4 zerov = {0.f,0.f,0.f,0.f};
#pragma unroll
  for(int i=0;i<4;i++)
#pragma unroll
    for(int j2=0;j2<4;j2++) fsum[i][j2] = zerov;

  stage(0, 0);
  stage(1, 1);
  asm volatile("s_waitcnt vmcnt(4)" ::: "memory");
  asm volatile("s_waitcnt lgkmcnt(0)" ::: "memory");
  __builtin_amdgcn_s_barrier();

  int cur = 0;
  for(int step = 0; step < 640; ++step){
    const __bf16* Ab = As + cur*4096;
    const __bf16* Bb = Bs + cur*4096;
    bf16x8 af[4], bg[4];
#pragma unroll
    for(int fi=0;fi<4;fi++){
      int R = wr*64 + fi*16 + lr16;
      af[fi] = *(const bf16x8*)(Ab + R*32 + ((quad ^ (R>>1)) & 3)*8);
    }
#pragma unroll
    for(int fj=0;fj<4;fj++){
      int N = wc*64 + fj*16 + lr16;
      bg[fj] = *(const bf16x8*)(Bb + N*32 + ((quad ^ (N>>1)) & 3)*8);
    }
    if(step + 2 < 640){
      int bi = cur + 2; if(bi >= 3) bi -= 3;
      stage(step + 2, bi);
    }
    if((step & 127) == 0){
      f32x4 onev = {1.f,1.f,1.f,1.f};
#pragma unroll
      for(int fi=0;fi<4;fi++)
#pragma unroll
        for(int fj=0;fj<4;fj++) prod[fi][fj] = onev;
    }
    if((step & 31) == 0){
      int rm = step >> 5;
#pragma unroll
      for(int fj=0;fj<4;fj++){
        float f0 = F0s[rm][wc*64 + fj*16 + lr16];
        f32x4 iv = {f0,f0,f0,f0};
#pragma unroll
        for(int fi=0;fi<4;fi++) acc[fi][fj] = iv;
      }
    }
    __builtin_amdgcn_s_setprio(1);
#pragma unroll
    for(int fi=0;fi<4;fi++)
#pragma unroll
      for(int fj=0;fj<4;fj++)
        acc[fi][fj] = __builtin_amdgcn_mfma_f32_16x16x32_bf16(af[fi], bg[fj], acc[fi][fj], 0,0,0);
    __builtin_amdgcn_s_setprio(0);
    if((step & 31) == 31){
      int mm = (step >> 5) & 3;
#pragma unroll
      for(int fi=0;fi<4;fi++)
#pragma unroll
        for(int reg=0;reg<4;reg++){
          float mk = Mskf[mm][wr*64 + fi*16 + quad*4 + reg];
#pragma unroll
          for(int fj=0;fj<4;fj++)
            prod[fi][fj][reg] *= (mk != 0.f) ? acc[fi][fj][reg] : 1.f;
        }
    }
    if((step & 127) == 127){
      float rw = Rws[step >> 7];
#pragma unroll
      for(int fi=0;fi<4;fi++)
#pragma unroll
        for(int fj=0;fj<4;fj++)
#pragma unroll
          for(int reg=0;reg<4;reg++)
            fsum[fi][fj][reg] += rw * prod[fi][fj][reg];
    }
    asm volatile("s_waitcnt lgkmcnt(0)" ::: "memory");
    if(step < 638) asm volatile("s_waitcnt vmcnt(4)" ::: "memory");
    else           asm volatile("s_waitcnt vmcnt(0)" ::: "memory");
    __builtin_amdgcn_s_barrier();
    cur = (cur + 1 == 3) ? 0 : cur + 1;
  }

#pragma unroll
  for(int fi=0;fi<4;fi++){
#pragma unroll
    for(int reg=0;reg<4;reg++){
      int row = row0 + wr*64 + fi*16 + quad*4 + reg;
#pragma unroll
      for(int fj=0;fj<4;fj++){
        int col = col0 + wc*64 + fj*16 + lr16;
        atomicAdd(&fused[(size_t)row*HH + col], fsum[fi][fj][reg]);
      }
    }
  }
}

// ---------------- row LayerNorm over H=1024 (fp32 out) ----------------------
__global__ void ln_row_k(const float* __restrict__ X, const float* __restrict__ w,
                         const float* __restrict__ bb, float* __restrict__ Y){
  int b=blockIdx.x, tid=threadIdx.x;
  __shared__ float sc[4];
  const float* x=X+(size_t)b*HH;
  float t[4]; float s=0.f,s2=0.f;
#pragma unroll
  for(int p=0;p<4;p++){ t[p]=x[tid+p*256]; s+=t[p]; s2+=t[p]*t[p]; }
  s=blockSum256(s,sc); s2=blockSum256(s2,sc);
  float mean=s/1024.f, rstd=rsqrtf(s2/1024.f-mean*mean+1e-5f);
#pragma unroll
  for(int p=0;p<4;p++){
    int h=tid+p*256;
    Y[(size_t)b*HH+h]=(t[p]-mean)*rstd*w[h]+bb[h];
  }
}
// ---------------- row LayerNorm over H=1024 (bf16 out) ----------------------
__global__ void ln_row_bf16_k(const float* __restrict__ X, const float* __restrict__ w,
                              const float* __restrict__ bb, __bf16* __restrict__ Y){
  int b=blockIdx.x, tid=threadIdx.x;
  __shared__ float sc[4];
  const float* x=X+(size_t)b*HH;
  float t[4]; float s=0.f,s2=0.f;
#pragma unroll
  for(int p=0;p<4;p++){ t[p]=x[tid+p*256]; s+=t[p]; s2+=t[p]*t[p]; }
  s=blockSum256(s,sc); s2=blockSum256(s2,sc);
  float mean=s/1024.f, rstd=rsqrtf(s2/1024.f-mean*mean+1e-5f);
#pragma unroll
  for(int p=0;p<4;p++){
    int h=tid+p*256;
    Y[(size_t)b*HH+h]=(__bf16)((t[p]-mean)*rstd*w[h]+bb[h]);
  }
}

// ---------------- launch ----------------------------------------------------
extern "C" void kernel_launch(void* const* d_in, const int* in_sizes, int n_in,
                              void* d_out, int out_size, void* d_ws, size_t ws_size,
                              hipStream_t stream) {
  const float* tokens   =(const float*)d_in[0];
  const int*   mask     =(const int*)  d_in[1];
  const float* ln_go_w  =(const float*)d_in[2];
  const float* ln_go_b  =(const float*)d_in[3];
  const float* go_w1    =(const float*)d_in[4];
  const float* go_b1    =(const float*)d_in[5];
  const float* go_w2    =(const float*)d_in[6];
  const float* go_b2    =(const float*)d_in[7];
  const float* ln_ga_w  =(const float*)d_in[8];
  const float* ln_ga_b  =(const float*)d_in[9];
  const float* ga_w1    =(const float*)d_in[10];
  const float* ga_b1    =(const float*)d_in[11];
  const float* ga_w2    =(const float*)d_in[12];
  const float* ga_b2    =(const float*)d_in[13];
  const float* a2o_w    =(const float*)d_in[14];
  const float* o2a_w    =(const float*)d_in[15];
  const float* ln_o_w   =(const float*)d_in[16];
  const float* ln_o_b   =(const float*)d_in[17];
  const float* ln_a_w   =(const float*)d_in[18];
  const float* ln_a_b   =(const float*)d_in[19];
  const float* factors  =(const float*)d_in[20];
  const float* rank_w   =(const float*)d_in[21];
  const float* lmf_bias =(const float*)d_in[22];
  const float* out_ln1_w=(const float*)d_in[23];
  const float* out_ln1_b=(const float*)d_in[24];
  const float* out_w    =(const float*)d_in[25];
  const float* out_b    =(const float*)d_in[26];
  const float* out_ln2_w=(const float*)d_in[27];
  const float* out_ln2_b=(const float*)d_in[28];
  float* out=(float*)d_out;

  char* wsp=(char*)d_ws; size_t off=0;
  auto alloc=[&](size_t bytes)->void*{
    void* p=wsp+off; off=(off+bytes+255)&~(size_t)255; return p;
  };
  __bf16* factT   =(__bf16*)alloc((size_t)4*RR*HH*HH*2);    // 84 MB
  __bf16* featGo  =(__bf16*)alloc((size_t)BB*3*D3*2);       // 75.5 MB
  __bf16* featGa  =(__bf16*)alloc((size_t)BB*D3*2);         // 25.2 MB
  float*  g_go_pre=(float*) alloc((size_t)BB*3*4);
  float*  ga_pre  =(float*) alloc((size_t)BB*4);
  float*  a2o     =(float*) alloc((size_t)BB*HH*4);
  __bf16* mixedB  =(__bf16*)alloc((size_t)BB*4*HH*2);
  __bf16* omeanB  =(__bf16*)alloc((size_t)BB*HH*2);
  __bf16* audioB  =(__bf16*)alloc((size_t)BB*HH*2);
  float*  o2a     =(float*) alloc((size_t)BB*HH*4);
  float*  fused   =(float*) alloc((size_t)BB*HH*4);
  __bf16* hbufB   =(__bf16*)alloc((size_t)BB*HH*2);
  __bf16* go_w1B  =(__bf16*)alloc((size_t)MIDD*D3*2);
  __bf16* ga_w1B  =(__bf16*)alloc((size_t)MIDD*D3*2);
  __bf16* a2o_wB  =(__bf16*)alloc((size_t)HH*HH*2);
  __bf16* o2a_wB  =(__bf16*)alloc((size_t)HH*HH*2);
  __bf16* out_wB  =(__bf16*)alloc((size_t)HH*HH*2);

  // 1) prep: weight converts + factor transpose + gate-others features
  prep_k<<<28672,256,0,stream>>>(go_w1,go_w1B, ga_w1,ga_w1B, a2o_w,a2o_wB,
                                 o2a_w,o2a_wB, out_w,out_wB,
                                 factors,factT,
                                 tokens,mask,ln_go_w,ln_go_b,featGo,audioB,g_go_pre);
  // 2) a2o GEMM || gate-others MLP (atomic) — one launch, both 128² tiles
  {
    GD dA = { audioB, a2o_wB, nullptr, a2o, nullptr, nullptr,
              HH, HH, HH, HH, 8, 32, 0 };          // 256 blocks
    GD dH = { featGo, go_w1B, go_b1, nullptr, go_w2, g_go_pre,
              D3, D3, 0, D3, 4, 96, 2 };           // 384 blocks
    gemm_dual_k<<<256+384,256,0,stream>>>(dA, dH, 256);
  }
  // 3) others_new + omeanB + featGa + ga_pre=0
  others_k<<<BB,256,0,stream>>>(tokens,mask,g_go_pre,go_b2,a2o,ln_o_w,ln_o_b,
                                ln_ga_w,ln_ga_b,mixedB,omeanB,featGa,ga_pre);
  // 4) gate-audio MLP (atomic) || o2a GEMM — one launch
  {
    GD dH = { featGa, ga_w1B, ga_b1, nullptr, ga_w2, ga_pre,
              D3, D3, 0, D3, 4, 32, 2 };           // 128 blocks
    GD dO = { omeanB, o2a_wB, nullptr, o2a, nullptr, nullptr,
              HH, HH, HH, HH, 8, 32, 0 };          // 256 blocks
    gemm_dual_k<<<128+256,256,0,stream>>>(dH, dO, 128);
  }
  // 5) mixed_audio -> mixedB slot 1; fused init to lmf_bias
  audio_k<<<BB,256,0,stream>>>(tokens,mask,ga_pre,ga_b2,o2a,ln_a_w,ln_a_b,mixedB,lmf_bias,fused);
  // 6) LMF: r-inside, atomic accumulate into fused (no P buffer)
  gemm_lmf2<<<dim3(8,32,2),256,0,stream>>>(mixedB,factT,factors,mask,rank_w,fused);
  // 7) hbufB = LN(fused) as bf16
  ln_row_bf16_k<<<BB,256,0,stream>>>(fused,out_ln1_w,out_ln1_b,hbufB);
  // 8) fused = gelu(hbufB @ out_w^T + out_b)
  {
    GD dO = { hbufB, out_wB, out_b, fused, nullptr, nullptr,
              HH, HH, HH, HH, 8, 32, 1 };          // 256 blocks
    gemm_dual_k<<<256,256,0,stream>>>(dO, dO, 256);
  }
  // 9) out = LN(fused)
  ln_row_k<<<BB,256,0,stream>>>(fused,out_ln2_w,out_ln2_b,out);
}